// Round 7
// baseline (373.977 us; speedup 1.0000x reference)
//
#include <hip/hip_runtime.h>

// LSTM_67980742362036: 2-layer LSTM (B=4096, T=200, I=32, H=6) + linear head.
// R15:
//  proj_v5: zero-LDS, zero-repeat-weight projection. History: proj_k (R12)
//    96 ds_read/row = LDS-throughput bound (75us); proj_k2 (R13) re-vector-
//    loaded weights per row (no scalarization, SGPR=32); proj_k3 (R14) fixed
//    weights (VGPR-resident) but staged x through LDS: 8 ds_read_b128 x 100
//    iters x 16 waves/CU x ~12cy = ~64us of LDS pipe. Now: weights in VGPR
//    (lane g%24 holds row g, loaded once) AND x via global loads with 2
//    distinct addrs/instr (lanes 0-23 row t, 24-47 row t+1, 48-63 dup row t).
//    Per 2 timesteps: 8 global_load_dwordx4 + 64 FMA-cy + 192B-contig store.
//    2-buffer ping-pong, static names (no runtime-indexed arrays).
//  scan_k5: R12's lstm_scan VERBATIM (1024 blocks, 4 batches/wave, swizzle
//    step). Measured packaging curve: 1/SIMD=760cy/step (best), 2/SIMD
//    half-inert=1044 (R14), 4/SIMD fat=1594 (R8). Keep the optimum.
// Fallback: proven R8 kernel if workspace too small.

#define TLEN  200
#define ISZ   32
#define HSZ   6
#define WPITCH 36

// ---- fallback (R8) LDS layout ----
#define RPITCH 25
#define RING_DW (64 * RPITCH)
#define FWOFF  RING_DW
#define FBOFF  (FWOFF + 24 * WPITCH)
#define FLDS_DW (FBOFF + 24)           // 9952 B

#define XP4_COUNT ((size_t)4096 * TLEN * 6)          // float4 elements
#define WS_REQ    ((XP4_COUNT + 6) * 16)             // + bias4 table

__device__ __forceinline__ float fast_sig(float x) {
    return __builtin_amdgcn_rcpf(1.0f + __expf(-x));
}
__device__ __forceinline__ float tanh_s(float x) {     // tanh via 2*sig(2x)-1
    return fmaf(2.0f, fast_sig(x + x), -1.0f);
}
__device__ __forceinline__ float rl(float v, int l) {
    return __int_as_float(__builtin_amdgcn_readlane(__float_as_int(v), l));
}
template <int CTRL>
__device__ __forceinline__ float qperm(float v) {
    return __int_as_float(__builtin_amdgcn_mov_dpp(__float_as_int(v), CTRL, 0xf, 0xf, true));
}
template <int OFF>
__device__ __forceinline__ float swz(float v) {        // BitMode group-broadcast
    return __int_as_float(__builtin_amdgcn_ds_swizzle(__float_as_int(v), OFF));
}
__device__ __forceinline__ float dot4(float4 w, float4 v) {
    return fmaf(w.x, v.x, fmaf(w.y, v.y, fmaf(w.z, v.z, w.w * v.w)));
}

// ======================= kernel 1: VGPR-weights, global-x projection =======================
__global__ __launch_bounds__(64) void proj_v5(
    const float* __restrict__ x,    const float* __restrict__ Wih0,
    const float* __restrict__ bih0, const float* __restrict__ bhh0,
    const float* __restrict__ bih1, const float* __restrict__ bhh1,
    float4* __restrict__ xp4)       // [b*200+t][u] (i,f,g,o); bias4 at XP4_COUNT
{
    const int lane = threadIdx.x;
    const int b    = blockIdx.x;

    if (b == 0 && lane < 24) {      // layer-1 folded bias table
        const int u = lane % 6, g = lane / 6;
        ((float*)(xp4 + XP4_COUNT))[u * 4 + g] = bih1[g * 6 + u] + bhh1[g * 6 + u];
    }

    // lanes 0-23: gate-row g, even timesteps; 24-47: gate-row g, odd; 48-63 inert
    const int  par = (lane >= 24 && lane < 48) ? 1 : 0;
    const int  g   = (lane < 24) ? lane : (lane < 48 ? lane - 24 : lane - 48);
    const bool act = (lane < 48);

    // weight row W[g][0..31] resident in 32 VGPRs (loaded once)
    float4 w4[8];
    const float4* wr = (const float4*)(Wih0 + g * ISZ);
#pragma unroll
    for (int q = 0; q < 8; ++q) w4[q] = wr[q];
    const float bg = bih0[g] + bhh0[g];

    // lane's row sequence r=0..99 -> timestep t = 2r+par, addr = xr + r*64
    const float* xr = x + (size_t)b * TLEN * ISZ + par * ISZ;
    float* xpb = (float*)(xp4 + (size_t)b * TLEN * 6);
    const int ofs = (g % 6) * 4 + g / 6;   // u*4 + gate within the 24-float row

    float4 A[8], B[8];
#pragma unroll
    for (int q = 0; q < 8; ++q) A[q] = ((const float4*)xr)[q];
#pragma unroll
    for (int q = 0; q < 8; ++q) B[q] = ((const float4*)(xr + 64))[q];

    // accumulation split identical to absmax-0 proj_k3: a0 = bias + k0..15,
    // a1 = k16..31, result = a0 + a1 (k ascending within each half).
#define PCOMP(BUF, R) do { \
    float a0 = bg, a1 = 0.0f; \
    _Pragma("unroll") \
    for (int q = 0; q < 4; ++q) { \
        a0 = fmaf(w4[q].x, BUF[q].x, a0); a0 = fmaf(w4[q].y, BUF[q].y, a0); \
        a0 = fmaf(w4[q].z, BUF[q].z, a0); a0 = fmaf(w4[q].w, BUF[q].w, a0); \
    } \
    _Pragma("unroll") \
    for (int q = 4; q < 8; ++q) { \
        a1 = fmaf(w4[q].x, BUF[q].x, a1); a1 = fmaf(w4[q].y, BUF[q].y, a1); \
        a1 = fmaf(w4[q].z, BUF[q].z, a1); a1 = fmaf(w4[q].w, BUF[q].w, a1); \
    } \
    const float a = a0 + a1; \
    if (act) xpb[(size_t)(2 * (R) + par) * 24 + ofs] = a; \
} while (0)

#pragma unroll 1
    for (int k = 0; k < 49; ++k) {
        PCOMP(A, 2 * k);
#pragma unroll
        for (int q = 0; q < 8; ++q) A[q] = ((const float4*)(xr + (2 * k + 2) * 64))[q];
        PCOMP(B, 2 * k + 1);
#pragma unroll
        for (int q = 0; q < 8; ++q) B[q] = ((const float4*)(xr + (2 * k + 3) * 64))[q];
    }
    PCOMP(A, 98);
    PCOMP(B, 99);
#undef PCOMP
}

// ======================= kernel 2: swizzle scan (R12 verbatim, 1024 blocks) =======================
__global__ __launch_bounds__(64) void scan_k5(
    const float* __restrict__ Whh0, const float* __restrict__ Wih1,
    const float* __restrict__ Whh1, const float* __restrict__ Wlin,
    const float* __restrict__ blin, const float4* __restrict__ xp4,
    float* __restrict__ out)
{
    const int lane = threadIdx.x;
    const int role = lane & 15;
    const int grp  = lane >> 4;
    const int b    = blockIdx.x * 4 + grp;

    // per-lane weights: WA = Whh0 (L0) / Wih1 (L1); WB = Whh1 (L1)
    float WA[4][6], WB[4][6];
#pragma unroll
    for (int gg = 0; gg < 4; ++gg)
#pragma unroll
        for (int k = 0; k < 6; ++k) { WA[gg][k] = 0.0f; WB[gg][k] = 0.0f; }
    if (role < 6) {
#pragma unroll
        for (int gg = 0; gg < 4; ++gg)
#pragma unroll
            for (int k = 0; k < 6; ++k) WA[gg][k] = Whh0[(gg * 6 + role) * 6 + k];
    } else if (role < 12) {
        const int u = role - 6;
#pragma unroll
        for (int gg = 0; gg < 4; ++gg)
#pragma unroll
            for (int k = 0; k < 6; ++k) {
                WA[gg][k] = Wih1[(gg * 6 + u) * 6 + k];
                WB[gg][k] = Whh1[(gg * 6 + u) * 6 + k];
            }
    }

    // xq stream: L0 lanes walk xp4; others pin a bias cell (ST=0)
    const float4* P;
    int ST;
    if (role < 6) { P = xp4 + (size_t)b * TLEN * 6 + role; ST = 6; }
    else          { P = xp4 + XP4_COUNT + (role < 12 ? role - 6 : 0); ST = 0; }

    float4 q0 = P[0], q1 = P[ST], q2 = P[2 * ST], q3 = P[3 * ST];
    P += 4 * ST;

    float c = 0.0f, h = 0.0f;

#define ARG(A, G) do { \
    const float s0 = fmaf(WA[G][0], hA0, fmaf(WA[G][1], hA1, fmaf(WA[G][2], hA2, A))); \
    const float s1 = fmaf(WA[G][3], hA3, fmaf(WA[G][4], hA4, WA[G][5] * hA5)); \
    const float s2 = fmaf(WB[G][0], hB0, fmaf(WB[G][1], hB1, WB[G][2] * hB2)); \
    const float s3 = fmaf(WB[G][3], hB3, fmaf(WB[G][4], hB4, WB[G][5] * hB5)); \
    A = (s0 + s1) + (s2 + s3); \
} while (0)

#define STEP(XQ) do { \
    const float hA0 = swz<0x010>(h), hA1 = swz<0x030>(h), hA2 = swz<0x050>(h); \
    const float hA3 = swz<0x070>(h), hA4 = swz<0x090>(h), hA5 = swz<0x0B0>(h); \
    const float hB0 = swz<0x0D0>(h), hB1 = swz<0x0F0>(h), hB2 = swz<0x110>(h); \
    const float hB3 = swz<0x130>(h), hB4 = swz<0x150>(h), hB5 = swz<0x170>(h); \
    float a0 = (XQ).x, a1 = (XQ).y, a2 = (XQ).z, a3 = (XQ).w; \
    ARG(a0, 0); ARG(a1, 1); ARG(a2, 2); ARG(a3, 3); \
    const float ig = fast_sig(a0), fg = fast_sig(a1); \
    const float gg = tanh_s(a2),   og = fast_sig(a3); \
    c = fmaf(fg, c, ig * gg); \
    h = og * tanh_s(c); \
} while (0)

#define STEPR(QV) do { const float4 _xq = QV; QV = *P; P += ST; STEP(_xq); } while (0)

    // s = 0 peel; erase phantom state of roles >= 6 (h1(-1) = 0)
    STEPR(q0);
    h = (role < 6) ? h : 0.0f;
    c = (role < 6) ? c : 0.0f;

    // s = 1..192 (48 x 4 rotating 4-deep prefetch)
#pragma unroll 1
    for (int m = 0; m < 48; ++m) {
        STEPR(q1); STEPR(q2); STEPR(q3); STEPR(q0);
    }
    // s = 193..200 tail
    STEPR(q1); STEPR(q2); STEPR(q3);
    STEP(q0); STEP(q1); STEP(q2); STEP(q3);
    STEP(q0);

    // linear head: h2_last lives on roles 6..11
    {
        const float f0 = swz<0x0D0>(h), f1 = swz<0x0F0>(h), f2 = swz<0x110>(h);
        const float f3 = swz<0x130>(h), f4 = swz<0x150>(h), f5 = swz<0x170>(h);
        float sOut = blin[0];
        sOut = fmaf(Wlin[0], f0, sOut); sOut = fmaf(Wlin[1], f1, sOut);
        sOut = fmaf(Wlin[2], f2, sOut); sOut = fmaf(Wlin[3], f3, sOut);
        sOut = fmaf(Wlin[4], f4, sOut); sOut = fmaf(Wlin[5], f5, sOut);
        if (role == 0) out[b] = sOut;
    }
#undef STEP
#undef STEPR
#undef ARG
}

// ======================= fallback: proven R8 kernel (135.5 us) =======================
__global__ __launch_bounds__(64) void lstm_fb(
    const float* __restrict__ x,
    const float* __restrict__ Wih0, const float* __restrict__ Whh0,
    const float* __restrict__ bih0, const float* __restrict__ bhh0,
    const float* __restrict__ Wih1, const float* __restrict__ Whh1,
    const float* __restrict__ bih1, const float* __restrict__ bhh1,
    const float* __restrict__ Wlin, const float* __restrict__ blin,
    float* __restrict__ out)
{
    __shared__ float lds[FLDS_DW];

    const int lane = threadIdx.x;
    const int b    = blockIdx.x;

    const int o = lane & 1;
    const int L = lane >> 1;

    const bool loHalf = (lane < 32);
    const int  p  = lane & 3;
    const int  jq = (lane & 31) >> 2;
    const int  j  = (jq < HSZ) ? jq : 0;
    const int  r  = 6 * p + j;

#define LDSW(ROW, KCQ) (*(const float4*)&lds[FWOFF + (o * 12 + (ROW)) * WPITCH + ((KCQ) << 2)])

#pragma unroll
    for (int k = 0; k < 13; ++k) {
        const int idx = lane + (k << 6);
        if (idx < 768) {
            const int row = idx >> 5, kk = idx & 31;
            lds[FWOFF + row * WPITCH + kk] = Wih0[idx];
        } else if (idx < 792) {
            lds[FBOFF + idx - 768] = bih0[idx - 768] + bhh0[idx - 768];
        }
    }

    float WA[6], WB[6], base1 = 0.0f, sgc = 1.0f, tgc = 0.0f;
#pragma unroll
    for (int k = 0; k < 6; ++k) { WA[k] = 0.0f; WB[k] = 0.0f; }
    if (loHalf) {
#pragma unroll
        for (int k = 0; k < 6; ++k) WA[k] = Whh0[r * 6 + k];
    } else {
#pragma unroll
        for (int k = 0; k < 6; ++k) { WA[k] = Wih1[r * 6 + k]; WB[k] = Whh1[r * 6 + k]; }
        base1 = bih1[r] + bhh1[r];
    }
    if (p == 2) {
#pragma unroll
        for (int k = 0; k < 6; ++k) { WA[k] *= 2.0f; WB[k] *= 2.0f; }
        base1 *= 2.0f; sgc = 2.0f; tgc = -1.0f;
    }

    const float* xb = x + (size_t)b * TLEN * ISZ;

#pragma unroll
    for (int w01 = 0; w01 < 2; ++w01) {
        const int t = (w01 << 5) + L;
        const float4* xr4 = (const float4*)(xb + t * ISZ);
        float4 xw[8];
#pragma unroll
        for (int q = 0; q < 8; ++q) xw[q] = xr4[q];
        float a0c[12];
#pragma unroll
        for (int jj = 0; jj < 12; ++jj) a0c[jj] = 0.0f;
#pragma unroll
        for (int kc = 0; kc < 8; ++kc)
#pragma unroll
            for (int jj = 0; jj < 12; ++jj)
                a0c[jj] += dot4(LDSW(jj, kc), xw[kc]);
#pragma unroll
        for (int jj = 0; jj < 12; ++jj) {
            float v = a0c[jj] + lds[FBOFF + o * 12 + jj];
            if (jj < 6) v = (o == 1) ? v * 2.0f : v;
            lds[t * RPITCH + o * 12 + jj] = v;
        }
    }

    float acc[12];
#pragma unroll
    for (int jj = 0; jj < 12; ++jj) acc[jj] = 0.0f;
    const float* pc = xb + (size_t)min(64 + L, TLEN - 1) * ISZ;
    const float* pn = xb + (size_t)min(96 + L, TLEN - 1) * ISZ;
    float4 f0, f1;
    f1 = *((const float4*)pc);
    float4 Wp0 = LDSW(0, 0), Wp1 = LDSW(1, 0), Wp2 = LDSW(2, 0);

    float c = 0.0f, h = 0.0f;
    float xp_cur = lds[r];

#define KC_HEAD(KC) do { \
    f0 = f1; \
    const float4* _srcp = ((KC) < 7) ? ((const float4*)pc + (KC) + 1) \
                                     : ((const float4*)pn); \
    f1 = *_srcp; \
} while (0)

#define SPREAD_STEP(RT, KC) do { \
    acc[3*(RT)+0] += dot4(Wp0, f0); \
    acc[3*(RT)+1] += dot4(Wp1, f0); \
    acc[3*(RT)+2] += dot4(Wp2, f0); \
    const int _rtn = ((RT) + 1) & 3; \
    const int _kcn = ((RT) == 3) ? (((KC) + 1) & 7) : (KC); \
    Wp0 = LDSW(3*_rtn + 0, _kcn); \
    Wp1 = LDSW(3*_rtn + 1, _kcn); \
    Wp2 = LDSW(3*_rtn + 2, _kcn); \
} while (0)

#define SCAN_STEP(ITV) do { \
    const float h10=rl(h,0),  h11=rl(h,4),  h12=rl(h,8); \
    const float h13=rl(h,12), h14=rl(h,16), h15=rl(h,20); \
    const float h20=rl(h,32), h21=rl(h,36), h22=rl(h,40); \
    const float h23=rl(h,44), h24=rl(h,48), h25=rl(h,52); \
    const float _xn = lds[(((ITV) + 1) & 63) * RPITCH + r]; \
    const float _g0 = loHalf ? xp_cur : base1; \
    const float _a0 = fmaf(WA[0],h10, fmaf(WA[2],h12, fmaf(WA[4],h14, _g0))); \
    const float _a1 = fmaf(WA[1],h11, fmaf(WA[3],h13, WA[5]*h15)); \
    const float _b0 = fmaf(WB[0],h20, fmaf(WB[2],h22, WB[4]*h24)); \
    const float _b1 = fmaf(WB[1],h21, fmaf(WB[3],h23, WB[5]*h25)); \
    const float _g  = (_a0 + _a1) + (_b0 + _b1); \
    const float _aG = fmaf(sgc, fast_sig(_g), tgc); \
    const float _iq = qperm<0x00>(_aG), _fq = qperm<0x55>(_aG); \
    const float _gq = qperm<0xAA>(_aG), _oq = qperm<0xFF>(_aG); \
    c = fmaf(_fq, c, _iq * _gq); \
    const float _th = fmaf(2.0f, fast_sig(2.0f * c), -1.0f); \
    h = _oq * _th; \
    xp_cur = _xn; \
    if ((ITV) == 200) { \
        float _s = blin[0]; \
        _s = fmaf(Wlin[0], rl(h, 32), _s); \
        _s = fmaf(Wlin[1], rl(h, 36), _s); \
        _s = fmaf(Wlin[2], rl(h, 40), _s); \
        _s = fmaf(Wlin[3], rl(h, 44), _s); \
        _s = fmaf(Wlin[4], rl(h, 48), _s); \
        _s = fmaf(Wlin[5], rl(h, 52), _s); \
        if (lane == 0) out[b] = _s; \
    } \
} while (0)

#define ENTRY(IT0) do { \
    const int _slot = ((IT0) + 32 + L) & 63; \
    _Pragma("unroll") \
    for (int _jj = 0; _jj < 12; ++_jj) { \
        float _v = acc[_jj] + lds[FBOFF + o * 12 + _jj]; \
        if (_jj < 6) _v = (o == 1) ? _v * 2.0f : _v; \
        lds[_slot * RPITCH + o * 12 + _jj] = _v; \
        acc[_jj] = 0.0f; \
    } \
    pc = pn; \
    pn = xb + (size_t)min((IT0) + 96 + L, TLEN - 1) * ISZ; \
} while (0)

    KC_HEAD(0);
    SPREAD_STEP(0, 0);
    {
        const float g  = loHalf ? xp_cur : base1;
        const float aG = fmaf(sgc, fast_sig(g), tgc);
        const float iq = qperm<0x00>(aG), gq = qperm<0xAA>(aG), oq = qperm<0xFF>(aG);
        const float cn = iq * gq;
        const float th = fmaf(2.0f, fast_sig(2.0f * cn), -1.0f);
        c = loHalf ? cn : 0.0f;
        h = loHalf ? (oq * th) : 0.0f;
        xp_cur = lds[RPITCH + r];
    }

    SPREAD_STEP(1, 0); SCAN_STEP(1);
    SPREAD_STEP(2, 0); SCAN_STEP(2);
    SPREAD_STEP(3, 0); SCAN_STEP(3);
    for (int kc = 1; kc < 8; ++kc) {
        KC_HEAD(kc);
        const int itb = kc << 2;
        SPREAD_STEP(0, kc); SCAN_STEP(itb + 0);
        SPREAD_STEP(1, kc); SCAN_STEP(itb + 1);
        SPREAD_STEP(2, kc); SCAN_STEP(itb + 2);
        SPREAD_STEP(3, kc); SCAN_STEP(itb + 3);
    }

    for (int w = 1; w < 7; ++w) {
        const int it0 = w << 5;
        ENTRY(it0);
        for (int kc = 0; kc < 8; ++kc) {
            const int itb = it0 + (kc << 2);
            if (itb > 200) break;
            KC_HEAD(kc);
            SPREAD_STEP(0, kc); SCAN_STEP(itb + 0);
            SPREAD_STEP(1, kc); SCAN_STEP(itb + 1);
            SPREAD_STEP(2, kc); SCAN_STEP(itb + 2);
            SPREAD_STEP(3, kc); SCAN_STEP(itb + 3);
        }
    }

#undef LDSW
#undef KC_HEAD
#undef SPREAD_STEP
#undef SCAN_STEP
#undef ENTRY
}

extern "C" void kernel_launch(void* const* d_in, const int* in_sizes, int n_in,
                              void* d_out, int out_size, void* d_ws, size_t ws_size,
                              hipStream_t stream) {
    const float* x    = (const float*)d_in[0];
    const float* Wih0 = (const float*)d_in[1];
    const float* Whh0 = (const float*)d_in[2];
    const float* bih0 = (const float*)d_in[3];
    const float* bhh0 = (const float*)d_in[4];
    const float* Wih1 = (const float*)d_in[5];
    const float* Whh1 = (const float*)d_in[6];
    const float* bih1 = (const float*)d_in[7];
    const float* bhh1 = (const float*)d_in[8];
    const float* Wlin = (const float*)d_in[9];
    const float* blin = (const float*)d_in[10];
    float* out = (float*)d_out;

    if (d_ws != nullptr && ws_size >= WS_REQ) {
        float4* xp4 = (float4*)d_ws;
        proj_v5<<<4096, 64, 0, stream>>>(x, Wih0, bih0, bhh0, bih1, bhh1, xp4);
        scan_k5<<<1024, 64, 0, stream>>>(Whh0, Wih1, Whh1, Wlin, blin,
                                         (const float4*)xp4, out);
    } else {
        lstm_fb<<<4096, 64, 0, stream>>>(x, Wih0, Whh0, bih0, bhh0,
                                         Wih1, Whh1, bih1, bhh1,
                                         Wlin, blin, out);
    }
}

// Round 8
// 264.451 us; speedup vs baseline: 1.4142x; 1.4142x over previous
//
#include <hip/hip_runtime.h>

// LSTM_67980742362036: 2-layer LSTM (B=4096, T=200, I=32, H=6) + linear head.
// R16:
//  proj_rl: lane-per-row projection with EXPLICIT weight scalarization.
//    Proj history: R12 weights-from-LDS 75us (LDS-pipe), R13 lane-per-row 80us
//    (compiler never scalarized the uniform weight loads, SGPR=32), R14
//    x-from-LDS 73us (LDS-pipe), R15 broadcast-global 175us (latency, VGPR=76
//    collapsed the ping-pong). Fix = R13's shape + manual scalarization:
//    the 768 Wih0 values live distributed across the wave (wv[12]/lane, loaded
//    once); each weight is broadcast with v_readlane at COMPILE-TIME lane
//    indices -> SGPR operand folded into v_fma. Zero weight re-reads, zero
//    LDS, perfectly coalesced x reads (8KB/wave) and per-lane-contiguous
//    96B stores. ~1600 VALU/lane one-shot; memory floor ~20-25us.
//  scan_k5: R12's scan VERBATIM (1024 blocks, 4 batches/wave, swizzle step;
//    measured optimum of the packaging curve 760cy/step).
// Fallback: proven R8 kernel if workspace too small.

#define TLEN  200
#define ISZ   32
#define HSZ   6
#define WPITCH 36

// ---- fallback (R8) LDS layout ----
#define RPITCH 25
#define RING_DW (64 * RPITCH)
#define FWOFF  RING_DW
#define FBOFF  (FWOFF + 24 * WPITCH)
#define FLDS_DW (FBOFF + 24)           // 9952 B

#define XP4_COUNT ((size_t)4096 * TLEN * 6)          // float4 elements
#define WS_REQ    ((XP4_COUNT + 6) * 16)             // + bias4 table

__device__ __forceinline__ float fast_sig(float x) {
    return __builtin_amdgcn_rcpf(1.0f + __expf(-x));
}
__device__ __forceinline__ float tanh_s(float x) {     // tanh via 2*sig(2x)-1
    return fmaf(2.0f, fast_sig(x + x), -1.0f);
}
__device__ __forceinline__ float rl(float v, int l) {
    return __int_as_float(__builtin_amdgcn_readlane(__float_as_int(v), l));
}
template <int CTRL>
__device__ __forceinline__ float qperm(float v) {
    return __int_as_float(__builtin_amdgcn_mov_dpp(__float_as_int(v), CTRL, 0xf, 0xf, true));
}
template <int OFF>
__device__ __forceinline__ float swz(float v) {        // BitMode group-broadcast
    return __int_as_float(__builtin_amdgcn_ds_swizzle(__float_as_int(v), OFF));
}
__device__ __forceinline__ float dot4(float4 w, float4 v) {
    return fmaf(w.x, v.x, fmaf(w.y, v.y, fmaf(w.z, v.z, w.w * v.w)));
}

// ======================= kernel 1: lane-per-row, readlane-scalarized weights =======================
__global__ __launch_bounds__(64) void proj_rl(
    const float* __restrict__ x,    const float* __restrict__ Wih0,
    const float* __restrict__ bih0, const float* __restrict__ bhh0,
    const float* __restrict__ bih1, const float* __restrict__ bhh1,
    float4* __restrict__ xp4)       // [b*200+t][u] (i,f,g,o); bias4 at XP4_COUNT
{
    const int lane = threadIdx.x;

    if (blockIdx.x == 0 && lane < 24) {     // layer-1 folded bias table
        const int u = lane % 6, g = lane / 6;
        ((float*)(xp4 + XP4_COUNT))[u * 4 + g] = bih1[g * 6 + u] + bhh1[g * 6 + u];
    }

    // wave-distributed weight copy: wv[k] on lane l holds Wih0[k*64 + l]
    float wv[12];
#pragma unroll
    for (int k = 0; k < 12; ++k) wv[k] = Wih0[(k << 6) + lane];
    // wave-distributed folded bias: lane g<24 holds bias[g]
    const float bv = (lane < 24) ? (bih0[lane] + bhh0[lane]) : 0.0f;

    // this lane's row: n = b*200 + t  (grid 12800*64 == 4096*200 exactly)
    const size_t n = (size_t)blockIdx.x * 64 + lane;
    float xs[32];
    {
        const float4* xr = (const float4*)(x + n * ISZ);
#pragma unroll
        for (int q = 0; q < 8; ++q) *(float4*)&xs[q << 2] = xr[q];   // 8KB/wave coalesced
    }

    // 24 gate rows: weight Wih0[g*32+c] lives in wv[g>>1] at lane (g&1)*32 + c
    // accumulation split matches absmax-0 proj_k3/v5: a0 = bias + c0..15,
    // a1 = c16..31, acc = a0 + a1 (c ascending in each half).
    float acc[24];
#pragma unroll
    for (int g = 0; g < 24; ++g) {
        const int base = (g & 1) << 5;
        float a0 = rl(bv, g);
        float a1 = 0.0f;
#pragma unroll
        for (int c = 0; c < 16; ++c)
            a0 = fmaf(rl(wv[g >> 1], base + c), xs[c], a0);
#pragma unroll
        for (int c = 16; c < 32; ++c)
            a1 = fmaf(rl(wv[g >> 1], base + c), xs[c], a1);
        acc[g] = a0 + a1;
    }

    // store: per-lane contiguous 96B, layout [n][u] = (i,f,g,o) per unit u
    float4* dst = xp4 + n * 6;
#pragma unroll
    for (int u = 0; u < 6; ++u)
        dst[u] = make_float4(acc[u], acc[6 + u], acc[12 + u], acc[18 + u]);
}

// ======================= kernel 2: swizzle scan (R12 verbatim, 1024 blocks) =======================
__global__ __launch_bounds__(64) void scan_k5(
    const float* __restrict__ Whh0, const float* __restrict__ Wih1,
    const float* __restrict__ Whh1, const float* __restrict__ Wlin,
    const float* __restrict__ blin, const float4* __restrict__ xp4,
    float* __restrict__ out)
{
    const int lane = threadIdx.x;
    const int role = lane & 15;
    const int grp  = lane >> 4;
    const int b    = blockIdx.x * 4 + grp;

    // per-lane weights: WA = Whh0 (L0) / Wih1 (L1); WB = Whh1 (L1)
    float WA[4][6], WB[4][6];
#pragma unroll
    for (int gg = 0; gg < 4; ++gg)
#pragma unroll
        for (int k = 0; k < 6; ++k) { WA[gg][k] = 0.0f; WB[gg][k] = 0.0f; }
    if (role < 6) {
#pragma unroll
        for (int gg = 0; gg < 4; ++gg)
#pragma unroll
            for (int k = 0; k < 6; ++k) WA[gg][k] = Whh0[(gg * 6 + role) * 6 + k];
    } else if (role < 12) {
        const int u = role - 6;
#pragma unroll
        for (int gg = 0; gg < 4; ++gg)
#pragma unroll
            for (int k = 0; k < 6; ++k) {
                WA[gg][k] = Wih1[(gg * 6 + u) * 6 + k];
                WB[gg][k] = Whh1[(gg * 6 + u) * 6 + k];
            }
    }

    // xq stream: L0 lanes walk xp4; others pin a bias cell (ST=0)
    const float4* P;
    int ST;
    if (role < 6) { P = xp4 + (size_t)b * TLEN * 6 + role; ST = 6; }
    else          { P = xp4 + XP4_COUNT + (role < 12 ? role - 6 : 0); ST = 0; }

    float4 q0 = P[0], q1 = P[ST], q2 = P[2 * ST], q3 = P[3 * ST];
    P += 4 * ST;

    float c = 0.0f, h = 0.0f;

#define ARG(A, G) do { \
    const float s0 = fmaf(WA[G][0], hA0, fmaf(WA[G][1], hA1, fmaf(WA[G][2], hA2, A))); \
    const float s1 = fmaf(WA[G][3], hA3, fmaf(WA[G][4], hA4, WA[G][5] * hA5)); \
    const float s2 = fmaf(WB[G][0], hB0, fmaf(WB[G][1], hB1, WB[G][2] * hB2)); \
    const float s3 = fmaf(WB[G][3], hB3, fmaf(WB[G][4], hB4, WB[G][5] * hB5)); \
    A = (s0 + s1) + (s2 + s3); \
} while (0)

#define STEP(XQ) do { \
    const float hA0 = swz<0x010>(h), hA1 = swz<0x030>(h), hA2 = swz<0x050>(h); \
    const float hA3 = swz<0x070>(h), hA4 = swz<0x090>(h), hA5 = swz<0x0B0>(h); \
    const float hB0 = swz<0x0D0>(h), hB1 = swz<0x0F0>(h), hB2 = swz<0x110>(h); \
    const float hB3 = swz<0x130>(h), hB4 = swz<0x150>(h), hB5 = swz<0x170>(h); \
    float a0 = (XQ).x, a1 = (XQ).y, a2 = (XQ).z, a3 = (XQ).w; \
    ARG(a0, 0); ARG(a1, 1); ARG(a2, 2); ARG(a3, 3); \
    const float ig = fast_sig(a0), fg = fast_sig(a1); \
    const float gg = tanh_s(a2),   og = fast_sig(a3); \
    c = fmaf(fg, c, ig * gg); \
    h = og * tanh_s(c); \
} while (0)

#define STEPR(QV) do { const float4 _xq = QV; QV = *P; P += ST; STEP(_xq); } while (0)

    // s = 0 peel; erase phantom state of roles >= 6 (h1(-1) = 0)
    STEPR(q0);
    h = (role < 6) ? h : 0.0f;
    c = (role < 6) ? c : 0.0f;

    // s = 1..192 (48 x 4 rotating 4-deep prefetch)
#pragma unroll 1
    for (int m = 0; m < 48; ++m) {
        STEPR(q1); STEPR(q2); STEPR(q3); STEPR(q0);
    }
    // s = 193..200 tail
    STEPR(q1); STEPR(q2); STEPR(q3);
    STEP(q0); STEP(q1); STEP(q2); STEP(q3);
    STEP(q0);

    // linear head: h2_last lives on roles 6..11
    {
        const float f0 = swz<0x0D0>(h), f1 = swz<0x0F0>(h), f2 = swz<0x110>(h);
        const float f3 = swz<0x130>(h), f4 = swz<0x150>(h), f5 = swz<0x170>(h);
        float sOut = blin[0];
        sOut = fmaf(Wlin[0], f0, sOut); sOut = fmaf(Wlin[1], f1, sOut);
        sOut = fmaf(Wlin[2], f2, sOut); sOut = fmaf(Wlin[3], f3, sOut);
        sOut = fmaf(Wlin[4], f4, sOut); sOut = fmaf(Wlin[5], f5, sOut);
        if (role == 0) out[b] = sOut;
    }
#undef STEP
#undef STEPR
#undef ARG
}

// ======================= fallback: proven R8 kernel (135.5 us) =======================
__global__ __launch_bounds__(64) void lstm_fb(
    const float* __restrict__ x,
    const float* __restrict__ Wih0, const float* __restrict__ Whh0,
    const float* __restrict__ bih0, const float* __restrict__ bhh0,
    const float* __restrict__ Wih1, const float* __restrict__ Whh1,
    const float* __restrict__ bih1, const float* __restrict__ bhh1,
    const float* __restrict__ Wlin, const float* __restrict__ blin,
    float* __restrict__ out)
{
    __shared__ float lds[FLDS_DW];

    const int lane = threadIdx.x;
    const int b    = blockIdx.x;

    const int o = lane & 1;
    const int L = lane >> 1;

    const bool loHalf = (lane < 32);
    const int  p  = lane & 3;
    const int  jq = (lane & 31) >> 2;
    const int  j  = (jq < HSZ) ? jq : 0;
    const int  r  = 6 * p + j;

#define LDSW(ROW, KCQ) (*(const float4*)&lds[FWOFF + (o * 12 + (ROW)) * WPITCH + ((KCQ) << 2)])

#pragma unroll
    for (int k = 0; k < 13; ++k) {
        const int idx = lane + (k << 6);
        if (idx < 768) {
            const int row = idx >> 5, kk = idx & 31;
            lds[FWOFF + row * WPITCH + kk] = Wih0[idx];
        } else if (idx < 792) {
            lds[FBOFF + idx - 768] = bih0[idx - 768] + bhh0[idx - 768];
        }
    }

    float WA[6], WB[6], base1 = 0.0f, sgc = 1.0f, tgc = 0.0f;
#pragma unroll
    for (int k = 0; k < 6; ++k) { WA[k] = 0.0f; WB[k] = 0.0f; }
    if (loHalf) {
#pragma unroll
        for (int k = 0; k < 6; ++k) WA[k] = Whh0[r * 6 + k];
    } else {
#pragma unroll
        for (int k = 0; k < 6; ++k) { WA[k] = Wih1[r * 6 + k]; WB[k] = Whh1[r * 6 + k]; }
        base1 = bih1[r] + bhh1[r];
    }
    if (p == 2) {
#pragma unroll
        for (int k = 0; k < 6; ++k) { WA[k] *= 2.0f; WB[k] *= 2.0f; }
        base1 *= 2.0f; sgc = 2.0f; tgc = -1.0f;
    }

    const float* xb = x + (size_t)b * TLEN * ISZ;

#pragma unroll
    for (int w01 = 0; w01 < 2; ++w01) {
        const int t = (w01 << 5) + L;
        const float4* xr4 = (const float4*)(xb + t * ISZ);
        float4 xw[8];
#pragma unroll
        for (int q = 0; q < 8; ++q) xw[q] = xr4[q];
        float a0c[12];
#pragma unroll
        for (int jj = 0; jj < 12; ++jj) a0c[jj] = 0.0f;
#pragma unroll
        for (int kc = 0; kc < 8; ++kc)
#pragma unroll
            for (int jj = 0; jj < 12; ++jj)
                a0c[jj] += dot4(LDSW(jj, kc), xw[kc]);
#pragma unroll
        for (int jj = 0; jj < 12; ++jj) {
            float v = a0c[jj] + lds[FBOFF + o * 12 + jj];
            if (jj < 6) v = (o == 1) ? v * 2.0f : v;
            lds[t * RPITCH + o * 12 + jj] = v;
        }
    }

    float acc[12];
#pragma unroll
    for (int jj = 0; jj < 12; ++jj) acc[jj] = 0.0f;
    const float* pc = xb + (size_t)min(64 + L, TLEN - 1) * ISZ;
    const float* pn = xb + (size_t)min(96 + L, TLEN - 1) * ISZ;
    float4 f0, f1;
    f1 = *((const float4*)pc);
    float4 Wp0 = LDSW(0, 0), Wp1 = LDSW(1, 0), Wp2 = LDSW(2, 0);

    float c = 0.0f, h = 0.0f;
    float xp_cur = lds[r];

#define KC_HEAD(KC) do { \
    f0 = f1; \
    const float4* _srcp = ((KC) < 7) ? ((const float4*)pc + (KC) + 1) \
                                     : ((const float4*)pn); \
    f1 = *_srcp; \
} while (0)

#define SPREAD_STEP(RT, KC) do { \
    acc[3*(RT)+0] += dot4(Wp0, f0); \
    acc[3*(RT)+1] += dot4(Wp1, f0); \
    acc[3*(RT)+2] += dot4(Wp2, f0); \
    const int _rtn = ((RT) + 1) & 3; \
    const int _kcn = ((RT) == 3) ? (((KC) + 1) & 7) : (KC); \
    Wp0 = LDSW(3*_rtn + 0, _kcn); \
    Wp1 = LDSW(3*_rtn + 1, _kcn); \
    Wp2 = LDSW(3*_rtn + 2, _kcn); \
} while (0)

#define SCAN_STEP(ITV) do { \
    const float h10=rl(h,0),  h11=rl(h,4),  h12=rl(h,8); \
    const float h13=rl(h,12), h14=rl(h,16), h15=rl(h,20); \
    const float h20=rl(h,32), h21=rl(h,36), h22=rl(h,40); \
    const float h23=rl(h,44), h24=rl(h,48), h25=rl(h,52); \
    const float _xn = lds[(((ITV) + 1) & 63) * RPITCH + r]; \
    const float _g0 = loHalf ? xp_cur : base1; \
    const float _a0 = fmaf(WA[0],h10, fmaf(WA[2],h12, fmaf(WA[4],h14, _g0))); \
    const float _a1 = fmaf(WA[1],h11, fmaf(WA[3],h13, WA[5]*h15)); \
    const float _b0 = fmaf(WB[0],h20, fmaf(WB[2],h22, WB[4]*h24)); \
    const float _b1 = fmaf(WB[1],h21, fmaf(WB[3],h23, WB[5]*h25)); \
    const float _g  = (_a0 + _a1) + (_b0 + _b1); \
    const float _aG = fmaf(sgc, fast_sig(_g), tgc); \
    const float _iq = qperm<0x00>(_aG), _fq = qperm<0x55>(_aG); \
    const float _gq = qperm<0xAA>(_aG), _oq = qperm<0xFF>(_aG); \
    c = fmaf(_fq, c, _iq * _gq); \
    const float _th = fmaf(2.0f, fast_sig(2.0f * c), -1.0f); \
    h = _oq * _th; \
    xp_cur = _xn; \
    if ((ITV) == 200) { \
        float _s = blin[0]; \
        _s = fmaf(Wlin[0], rl(h, 32), _s); \
        _s = fmaf(Wlin[1], rl(h, 36), _s); \
        _s = fmaf(Wlin[2], rl(h, 40), _s); \
        _s = fmaf(Wlin[3], rl(h, 44), _s); \
        _s = fmaf(Wlin[4], rl(h, 48), _s); \
        _s = fmaf(Wlin[5], rl(h, 52), _s); \
        if (lane == 0) out[b] = _s; \
    } \
} while (0)

#define ENTRY(IT0) do { \
    const int _slot = ((IT0) + 32 + L) & 63; \
    _Pragma("unroll") \
    for (int _jj = 0; _jj < 12; ++_jj) { \
        float _v = acc[_jj] + lds[FBOFF + o * 12 + _jj]; \
        if (_jj < 6) _v = (o == 1) ? _v * 2.0f : _v; \
        lds[_slot * RPITCH + o * 12 + _jj] = _v; \
        acc[_jj] = 0.0f; \
    } \
    pc = pn; \
    pn = xb + (size_t)min((IT0) + 96 + L, TLEN - 1) * ISZ; \
} while (0)

    KC_HEAD(0);
    SPREAD_STEP(0, 0);
    {
        const float g  = loHalf ? xp_cur : base1;
        const float aG = fmaf(sgc, fast_sig(g), tgc);
        const float iq = qperm<0x00>(aG), gq = qperm<0xAA>(aG), oq = qperm<0xFF>(aG);
        const float cn = iq * gq;
        const float th = fmaf(2.0f, fast_sig(2.0f * cn), -1.0f);
        c = loHalf ? cn : 0.0f;
        h = loHalf ? (oq * th) : 0.0f;
        xp_cur = lds[RPITCH + r];
    }

    SPREAD_STEP(1, 0); SCAN_STEP(1);
    SPREAD_STEP(2, 0); SCAN_STEP(2);
    SPREAD_STEP(3, 0); SCAN_STEP(3);
    for (int kc = 1; kc < 8; ++kc) {
        KC_HEAD(kc);
        const int itb = kc << 2;
        SPREAD_STEP(0, kc); SCAN_STEP(itb + 0);
        SPREAD_STEP(1, kc); SCAN_STEP(itb + 1);
        SPREAD_STEP(2, kc); SCAN_STEP(itb + 2);
        SPREAD_STEP(3, kc); SCAN_STEP(itb + 3);
    }

    for (int w = 1; w < 7; ++w) {
        const int it0 = w << 5;
        ENTRY(it0);
        for (int kc = 0; kc < 8; ++kc) {
            const int itb = it0 + (kc << 2);
            if (itb > 200) break;
            KC_HEAD(kc);
            SPREAD_STEP(0, kc); SCAN_STEP(itb + 0);
            SPREAD_STEP(1, kc); SCAN_STEP(itb + 1);
            SPREAD_STEP(2, kc); SCAN_STEP(itb + 2);
            SPREAD_STEP(3, kc); SCAN_STEP(itb + 3);
        }
    }

#undef LDSW
#undef KC_HEAD
#undef SPREAD_STEP
#undef SCAN_STEP
#undef ENTRY
}

extern "C" void kernel_launch(void* const* d_in, const int* in_sizes, int n_in,
                              void* d_out, int out_size, void* d_ws, size_t ws_size,
                              hipStream_t stream) {
    const float* x    = (const float*)d_in[0];
    const float* Wih0 = (const float*)d_in[1];
    const float* Whh0 = (const float*)d_in[2];
    const float* bih0 = (const float*)d_in[3];
    const float* bhh0 = (const float*)d_in[4];
    const float* Wih1 = (const float*)d_in[5];
    const float* Whh1 = (const float*)d_in[6];
    const float* bih1 = (const float*)d_in[7];
    const float* bhh1 = (const float*)d_in[8];
    const float* Wlin = (const float*)d_in[9];
    const float* blin = (const float*)d_in[10];
    float* out = (float*)d_out;

    if (d_ws != nullptr && ws_size >= WS_REQ) {
        float4* xp4 = (float4*)d_ws;
        proj_rl<<<12800, 64, 0, stream>>>(x, Wih0, bih0, bhh0, bih1, bhh1, xp4);
        scan_k5<<<1024, 64, 0, stream>>>(Whh0, Wih1, Whh1, Wlin, blin,
                                         (const float4*)xp4, out);
    } else {
        lstm_fb<<<4096, 64, 0, stream>>>(x, Wih0, Whh0, bih0, bhh0,
                                         Wih1, Whh1, bih1, bhh1,
                                         Wlin, blin, out);
    }
}